// Round 8
// baseline (216.159 us; speedup 1.0000x reference)
//
#include <hip/hip_runtime.h>
#include <math.h>

#define B_ 4
#define S_ 2048
#define D_ 512
#define H_ 8
#define HD_ 64
#define SZ_ (B_ * S_ * D_)
#define WSZ_ (D_ * D_)   // 262144
#define BSH_ (B_ * S_ * H_)

// 0.125 * log2(e): folds the 1/sqrt(64) score scale and exp->exp2 into Qh.
#define QSCALE_ 0.18033688011112042f

typedef _Float16 v4h __attribute__((ext_vector_type(4)));
typedef _Float16 v8h __attribute__((ext_vector_type(8)));
typedef float    v4f __attribute__((ext_vector_type(4)));

// Async global->LDS 16B DMA (m97 pattern). LDS dest = wave-uniform base + lane*16.
#define GLD16(g, l)                                                         \
    __builtin_amdgcn_global_load_lds(                                       \
        (const __attribute__((address_space(1))) unsigned int*)(g),         \
        (__attribute__((address_space(3))) unsigned int*)(l), 16, 0, 0)

// ---------------------------------------------------------------------------
// W[k][n] fp32 -> Wt[n][k] f16 (n-major so MFMA B-frags read contiguous k).
// ---------------------------------------------------------------------------
__global__ __launch_bounds__(256) void wtrans_kernel(const float* __restrict__ Wq,
                                                     const float* __restrict__ Wo,
                                                     _Float16* __restrict__ Wt) {
    __shared__ float Ts[64][65];
    const float* W = blockIdx.z ? Wo : Wq;
    _Float16* dst = Wt + (size_t)blockIdx.z * WSZ_;
    const int t = threadIdx.x;
    const int k0 = blockIdx.y * 64, n0 = blockIdx.x * 64;
#pragma unroll
    for (int i = 0; i < 4; i++) {
        int c = t + i * 256;
        int kk = c >> 4, nc = (c & 15) * 4;
        float4 w = *(const float4*)&W[(size_t)(k0 + kk) * 512 + n0 + nc];
        Ts[nc + 0][kk] = w.x;
        Ts[nc + 1][kk] = w.y;
        Ts[nc + 2][kk] = w.z;
        Ts[nc + 3][kk] = w.w;
    }
    __syncthreads();
#pragma unroll
    for (int i = 0; i < 2; i++) {
        int c = t + i * 256;
        int n = c >> 3, kc = (c & 7) * 8;
        v8h p;
#pragma unroll
        for (int j = 0; j < 8; j++) p[j] = (_Float16)Ts[n][kc + j];
        *(v8h*)&dst[(size_t)(n0 + n) * 512 + k0 + kc] = p;
    }
}

// ---------------------------------------------------------------------------
// Projection: fused cast. A staged from fp32 global with in-register f32->f16
// convert; B (pre-transposed f16 weights) via async GLD16. 128x128 tile,
// BK=32, 4 waves (2x2), wave = 64x64.
// z in {0,1,2} -> Qh (pre-scaled) / Kh / VT [B,H,HD,S(permuted)].
// VT key permutation per 64-tile: key=kb*16+qk*4+r -> pos=(kb>>1)*32+qk*8+(kb&1)*4+r
// so flash PV reads two 16-key A-frags per ds_read_b128.
// ---------------------------------------------------------------------------
__global__ __launch_bounds__(256) void proj_mfma(const float* __restrict__ q,
                                                 const float* __restrict__ k,
                                                 const float* __restrict__ v,
                                                 const _Float16* __restrict__ Wt,
                                                 const float* __restrict__ bq,
                                                 _Float16* __restrict__ Qh,
                                                 _Float16* __restrict__ Kh,
                                                 _Float16* __restrict__ VT) {
    __shared__ _Float16 As[128 * 32];
    __shared__ _Float16 Bs[128 * 32];
    const int z  = blockIdx.z;
    const float* X = (z == 0) ? q : ((z == 1) ? k : v);
    const int n0 = blockIdx.x * 128, m0 = blockIdx.y * 128;
    const int t    = threadIdx.x;
    const int lane = t & 63;
    const int w    = t >> 6;
    const int wm   = w >> 1, wn = w & 1;
    const int quad = lane >> 4, l16 = lane & 15;

    v4f acc[4][4];
#pragma unroll
    for (int mi = 0; mi < 4; mi++)
#pragma unroll
        for (int ni = 0; ni < 4; ni++) acc[mi][ni] = (v4f)0.f;

    const int s0 = t, s1 = t + 256;
    const int r0 = s0 >> 2, c0 = (s0 & 3) * 8;
    const int r1 = s1 >> 2, c1 = (s1 & 3) * 8;
    const float* A0 = X + (size_t)(m0 + r0) * 512 + c0;
    const float* A1 = X + (size_t)(m0 + r1) * 512 + c1;
    const _Float16* B0 = Wt + (size_t)(n0 + r0) * 512 + c0;
    const _Float16* B1 = Wt + (size_t)(n0 + r1) * 512 + c1;

    for (int k0 = 0; k0 < 512; k0 += 32) {
        // A loads issue before the barrier: latency overlaps prior compute
        v4f a00 = *(const v4f*)(A0 + k0);
        v4f a01 = *(const v4f*)(A0 + k0 + 4);
        v4f a10 = *(const v4f*)(A1 + k0);
        v4f a11 = *(const v4f*)(A1 + k0 + 4);
        __syncthreads();   // previous iteration's frag reads complete
        GLD16(B0 + k0, &Bs[s0 * 8]);
        GLD16(B1 + k0, &Bs[s1 * 8]);
        v4h p0lo = __builtin_convertvector(a00, v4h);
        v4h p0hi = __builtin_convertvector(a01, v4h);
        v4h p1lo = __builtin_convertvector(a10, v4h);
        v4h p1hi = __builtin_convertvector(a11, v4h);
        *(v8h*)&As[s0 * 8] = __builtin_shufflevector(p0lo, p0hi, 0, 1, 2, 3, 4, 5, 6, 7);
        *(v8h*)&As[s1 * 8] = __builtin_shufflevector(p1lo, p1hi, 0, 1, 2, 3, 4, 5, 6, 7);
        __syncthreads();   // drains lgkm + vmcnt: staging complete

        v8h af[4], bf[4];
#pragma unroll
        for (int mi = 0; mi < 4; mi++)
            af[mi] = *(const v8h*)&As[(wm * 64 + mi * 16 + l16) * 32 + quad * 8];
#pragma unroll
        for (int ni = 0; ni < 4; ni++)
            bf[ni] = *(const v8h*)&Bs[(wn * 64 + ni * 16 + l16) * 32 + quad * 8];
#pragma unroll
        for (int mi = 0; mi < 4; mi++)
#pragma unroll
            for (int ni = 0; ni < 4; ni++)
                acc[mi][ni] = __builtin_amdgcn_mfma_f32_16x16x32_f16(af[mi], bf[ni], acc[mi][ni], 0, 0, 0);
    }

    if (z < 2) {
        _Float16* Y = z ? Kh : Qh;
        const float sc = z ? 1.f : QSCALE_;
#pragma unroll
        for (int mi = 0; mi < 4; mi++) {
            int mb = m0 + wm * 64 + mi * 16 + quad * 4;
#pragma unroll
            for (int ni = 0; ni < 4; ni++) {
                int n = n0 + wn * 64 + ni * 16 + l16;
                float bj = bq[n];
#pragma unroll
                for (int r = 0; r < 4; r++)
                    Y[(size_t)(mb + r) * 512 + n] = (_Float16)((acc[mi][ni][r] + bj) * sc);
            }
        }
    } else {
#pragma unroll
        for (int mi = 0; mi < 4; mi++) {
            int tile0 = (m0 & 2047) + wm * 64;
            int pos = tile0 + (mi >> 1) * 32 + quad * 8 + (mi & 1) * 4;
            int b = m0 >> 11;
#pragma unroll
            for (int ni = 0; ni < 4; ni++) {
                int n = n0 + wn * 64 + ni * 16 + l16;
                int h = n >> 6, d = n & 63;
                float bj = bq[n];
                v4h pk;
#pragma unroll
                for (int r = 0; r < 4; r++) pk[r] = (_Float16)(acc[mi][ni][r] + bj);
                *(v4h*)&VT[(((size_t)b * H_ + h) * HD_ + d) * S_ + pos] = pk;
            }
        }
    }
}

// ---------------------------------------------------------------------------
// Output projection with FUSED split-K combine: A[m,k] = (O1+O2)[m,k] * linv
// computed during staging (linear in the GEMM -> exactly equivalent).
// ---------------------------------------------------------------------------
__global__ __launch_bounds__(256) void outproj_mfma(const float* __restrict__ Op,
                                                    const float* __restrict__ lp,
                                                    const _Float16* __restrict__ Wt,
                                                    const float* __restrict__ bo,
                                                    float* __restrict__ out) {
    __shared__ _Float16 As[128 * 32];
    __shared__ _Float16 Bs[128 * 32];
    const int n0 = blockIdx.x * 128, m0 = blockIdx.y * 128;
    const int t    = threadIdx.x;
    const int lane = t & 63;
    const int w    = t >> 6;
    const int wm   = w >> 1, wn = w & 1;
    const int quad = lane >> 4, l16 = lane & 15;

    v4f acc[4][4];
#pragma unroll
    for (int mi = 0; mi < 4; mi++)
#pragma unroll
        for (int ni = 0; ni < 4; ni++) acc[mi][ni] = (v4f)0.f;

    const int s0 = t, s1 = t + 256;
    const int r0 = s0 >> 2, c0 = (s0 & 3) * 8;
    const int r1 = s1 >> 2, c1 = (s1 & 3) * 8;
    const float* O10 = Op + (size_t)(m0 + r0) * 512 + c0;
    const float* O11 = Op + (size_t)(m0 + r1) * 512 + c1;
    const float* O20 = O10 + SZ_;
    const float* O21 = O11 + SZ_;
    const float* lp10 = lp + (size_t)(m0 + r0) * H_;
    const float* lp11 = lp + (size_t)(m0 + r1) * H_;
    const _Float16* B0 = Wt + (size_t)WSZ_ + (size_t)(n0 + r0) * 512 + c0;
    const _Float16* B1 = Wt + (size_t)WSZ_ + (size_t)(n0 + r1) * 512 + c1;

    for (int k0 = 0; k0 < 512; k0 += 32) {
        const int hh = k0 >> 6;   // c0,c1 < 64 and (k0&63)+24 < 64 -> uniform per iter
        v4f a00 = *(const v4f*)(O10 + k0);
        v4f a01 = *(const v4f*)(O10 + k0 + 4);
        v4f a10 = *(const v4f*)(O11 + k0);
        v4f a11 = *(const v4f*)(O11 + k0 + 4);
        v4f b00 = *(const v4f*)(O20 + k0);
        v4f b01 = *(const v4f*)(O20 + k0 + 4);
        v4f b10 = *(const v4f*)(O21 + k0);
        v4f b11 = *(const v4f*)(O21 + k0 + 4);
        float linv0 = __builtin_amdgcn_rcpf(lp10[hh] + lp10[BSH_ + hh]);
        float linv1 = __builtin_amdgcn_rcpf(lp11[hh] + lp11[BSH_ + hh]);
        __syncthreads();
        GLD16(B0 + k0, &Bs[s0 * 8]);
        GLD16(B1 + k0, &Bs[s1 * 8]);
        v4f s0a = (a00 + b00) * linv0, s0b = (a01 + b01) * linv0;
        v4f s1a = (a10 + b10) * linv1, s1b = (a11 + b11) * linv1;
        v4h p0lo = __builtin_convertvector(s0a, v4h);
        v4h p0hi = __builtin_convertvector(s0b, v4h);
        v4h p1lo = __builtin_convertvector(s1a, v4h);
        v4h p1hi = __builtin_convertvector(s1b, v4h);
        *(v8h*)&As[s0 * 8] = __builtin_shufflevector(p0lo, p0hi, 0, 1, 2, 3, 4, 5, 6, 7);
        *(v8h*)&As[s1 * 8] = __builtin_shufflevector(p1lo, p1hi, 0, 1, 2, 3, 4, 5, 6, 7);
        __syncthreads();

        v8h af[4], bf[4];
#pragma unroll
        for (int mi = 0; mi < 4; mi++)
            af[mi] = *(const v8h*)&As[(wm * 64 + mi * 16 + l16) * 32 + quad * 8];
#pragma unroll
        for (int ni = 0; ni < 4; ni++)
            bf[ni] = *(const v8h*)&Bs[(wn * 64 + ni * 16 + l16) * 32 + quad * 8];
#pragma unroll
        for (int mi = 0; mi < 4; mi++)
#pragma unroll
            for (int ni = 0; ni < 4; ni++)
                acc[mi][ni] = __builtin_amdgcn_mfma_f32_16x16x32_f16(af[mi], bf[ni], acc[mi][ni], 0, 0, 0);
    }

#pragma unroll
    for (int mi = 0; mi < 4; mi++) {
        int mb = m0 + wm * 64 + mi * 16 + quad * 4;
#pragma unroll
        for (int ni = 0; ni < 4; ni++) {
            int n = n0 + wn * 64 + ni * 16 + l16;
            float bj = bo[n];
#pragma unroll
            for (int r = 0; r < 4; r++)
                out[(size_t)(mb + r) * 512 + n] = acc[mi][ni][r] + bj;
        }
    }
}

// ---------------------------------------------------------------------------
// Split-K MFMA f16 flash attention (no-max exp2 softmax -> partials additive).
// Wave owns 32 q-rows; block = 4 waves = 128 q-rows over 1024 keys.
// NEW (R8): next K/V tile prefetched into VGPRs before compute of the current
// tile — global latency overlaps MFMA/VALU instead of stalling at the barrier.
// ---------------------------------------------------------------------------
__global__ __launch_bounds__(256) void flash_attn_f16(const _Float16* __restrict__ Qh,
                                                      const _Float16* __restrict__ Kh,
                                                      const _Float16* __restrict__ VT,
                                                      float* __restrict__ Op,
                                                      float* __restrict__ lp) {
    __shared__ _Float16 Ks[128 * 72];    // [key][d], pad 72
    __shared__ _Float16 Vs[64 * 136];    // [d][pos], pad 136

    const int t     = threadIdx.x;
    const int lane  = t & 63;
    const int w     = t >> 6;
    const int quad  = lane >> 4;
    const int l16   = lane & 15;
    const int q0    = blockIdx.x * 128;
    const int h     = blockIdx.y;
    const int b     = blockIdx.z >> 1;
    const int split = blockIdx.z & 1;

    const size_t base  = (size_t)b * S_ * D_ + (size_t)h * HD_;
    const size_t vbase = ((size_t)b * H_ + h) * HD_ * (size_t)S_;

    // Persistent Q fragments: B-operand of 16x16x32 (n = qrow = l16)
    v8h qf[2][2];
#pragma unroll
    for (int nb = 0; nb < 2; nb++) {
        const _Float16* qrow = Qh + base + (size_t)(q0 + w * 32 + nb * 16 + l16) * D_;
        qf[nb][0] = *(const v8h*)(qrow + quad * 8);
        qf[nb][1] = *(const v8h*)(qrow + 32 + quad * 8);
    }

    v4f o[2][4];
#pragma unroll
    for (int nb = 0; nb < 2; nb++)
#pragma unroll
        for (int i = 0; i < 4; i++) o[nb][i] = (v4f)0.f;
    float l_lane[2] = {0.f, 0.f};

    const int kbeg = split * (S_ / 2);
    const int kend = kbeg + S_ / 2;

    v8h kv[4], vv[4];
#define LOADKV(kk)                                                             \
    do {                                                                       \
        _Pragma("unroll") for (int i = 0; i < 4; i++) {                        \
            int c = t + i * 256;                                               \
            kv[i] = *(const v8h*)(Kh + base + (size_t)((kk) + (c >> 3)) * D_ + (c & 7) * 8); \
            vv[i] = *(const v8h*)(VT + vbase + (size_t)(c >> 4) * S_ + (kk) + (c & 15) * 8); \
        }                                                                      \
    } while (0)

    LOADKV(kbeg);   // prologue

    for (int kk0 = kbeg; kk0 < kend; kk0 += 128) {
        __syncthreads();   // previous iteration's LDS reads complete
#pragma unroll
        for (int i = 0; i < 4; i++) {
            int c = t + i * 256;
            *(v8h*)&Ks[(c >> 3) * 72 + (c & 7) * 8] = kv[i];
            *(v8h*)&Vs[(c >> 4) * 136 + (c & 15) * 8] = vv[i];
        }
        __syncthreads();

        if (kk0 + 128 < kend) LOADKV(kk0 + 128);   // prefetch next tile

        // Two 64-key halves
#pragma unroll
        for (int hh = 0; hh < 2; hh++) {
            v4f sc[4][2];
#pragma unroll
            for (int mb = 0; mb < 4; mb++)
#pragma unroll
                for (int nb = 0; nb < 2; nb++) sc[mb][nb] = (v4f)0.f;
#pragma unroll
            for (int ks = 0; ks < 2; ks++) {
#pragma unroll
                for (int mb = 0; mb < 4; mb++) {
                    v8h ak = *(const v8h*)&Ks[(hh * 64 + mb * 16 + l16) * 72 + ks * 32 + quad * 8];
#pragma unroll
                    for (int nb = 0; nb < 2; nb++)
                        sc[mb][nb] = __builtin_amdgcn_mfma_f32_16x16x32_f16(ak, qf[nb][ks], sc[mb][nb], 0, 0, 0);
                }
            }

            // P = exp2(S): raw v_exp_f32, per-lane partial sums
            v4h pf[4][2];
#pragma unroll
            for (int nb = 0; nb < 2; nb++) {
#pragma unroll
                for (int mb = 0; mb < 4; mb++) {
                    v4f pv;
#pragma unroll
                    for (int r = 0; r < 4; r++) pv[r] = __builtin_amdgcn_exp2f(sc[mb][nb][r]);
                    pf[mb][nb] = __builtin_convertvector(pv, v4h);
                    l_lane[nb] += (pv[0] + pv[1]) + (pv[2] + pv[3]);
                }
            }

            // O^T += V^T · P^T ; one b128 V read covers kb=2p and 2p+1
#pragma unroll
            for (int p = 0; p < 2; p++) {
#pragma unroll
                for (int dblk = 0; dblk < 4; dblk++) {
                    v8h vf2 = *(const v8h*)&Vs[(dblk * 16 + l16) * 136 + hh * 64 + p * 32 + quad * 8];
                    v4h vlo = __builtin_shufflevector(vf2, vf2, 0, 1, 2, 3);
                    v4h vhi = __builtin_shufflevector(vf2, vf2, 4, 5, 6, 7);
#pragma unroll
                    for (int nb = 0; nb < 2; nb++) {
                        o[nb][dblk] = __builtin_amdgcn_mfma_f32_16x16x16f16(vlo, pf[2 * p][nb], o[nb][dblk], 0, 0, 0);
                        o[nb][dblk] = __builtin_amdgcn_mfma_f32_16x16x16f16(vhi, pf[2 * p + 1][nb], o[nb][dblk], 0, 0, 0);
                    }
                }
            }
        }
    }
#undef LOADKV

    // Final l reduction + unnormalized partial stores
    float* Ops = Op + (size_t)split * SZ_;
#pragma unroll
    for (int nb = 0; nb < 2; nb++) {
        float rs = l_lane[nb];
        rs += __shfl_xor(rs, 16);
        rs += __shfl_xor(rs, 32);
        int qrow = q0 + w * 32 + nb * 16 + l16;
        if (quad == 0)
            lp[(size_t)split * BSH_ + ((size_t)b * S_ + qrow) * H_ + h] = rs;
        const size_t rbase = base + (size_t)qrow * D_;
#pragma unroll
        for (int dblk = 0; dblk < 4; dblk++)
            *(v4f*)&Ops[rbase + dblk * 16 + quad * 4] = o[nb][dblk];
    }
}

extern "C" void kernel_launch(void* const* d_in, const int* in_sizes, int n_in,
                              void* d_out, int out_size, void* d_ws, size_t ws_size,
                              hipStream_t stream) {
    const float* query = (const float*)d_in[0];
    const float* key   = (const float*)d_in[1];
    const float* value = (const float*)d_in[2];
    const float* Wq    = (const float*)d_in[3];
    const float* bq    = (const float*)d_in[4];
    const float* Wo    = (const float*)d_in[5];
    const float* bo    = (const float*)d_in[6];
    float* out = (float*)d_out;

    _Float16* ws = (_Float16*)d_ws;
    _Float16* Qh = ws;                                   // [B,S,D] f16
    _Float16* Kh = ws + (size_t)SZ_;                     // [B,S,D] f16
    _Float16* VT = ws + 2 * (size_t)SZ_;                 // [B,H,HD,S] f16 (permuted)
    _Float16* Wt = ws + 3 * (size_t)SZ_;                 // 2x[N,K] f16
    float*    Op = (float*)(ws + 3 * (size_t)SZ_ + 2 * (size_t)WSZ_);  // 2x[B,S,D] f32
    float*    lp = Op + 2 * (size_t)SZ_;                 // 2x[B,S,H] f32

    wtrans_kernel<<<dim3(8, 8, 2), 256, 0, stream>>>(Wq, Wo, Wt);
    proj_mfma<<<dim3(4, 64, 3), 256, 0, stream>>>(query, key, value, Wt, bq, Qh, Kh, VT);
    flash_attn_f16<<<dim3(S_ / 128, H_, B_ * 2), 256, 0, stream>>>(Qh, Kh, VT, Op, lp);
    outproj_mfma<<<dim3(4, 64, 1), 256, 0, stream>>>(Op, lp, Wt, bo, out);
}

// Round 9
// 211.680 us; speedup vs baseline: 1.0212x; 1.0212x over previous
//
#include <hip/hip_runtime.h>
#include <math.h>

#define B_ 4
#define S_ 2048
#define D_ 512
#define H_ 8
#define HD_ 64
#define SZ_ (B_ * S_ * D_)
#define WSZ_ (D_ * D_)   // 262144
#define BSH_ (B_ * S_ * H_)

// 0.125 * log2(e): folds the 1/sqrt(64) score scale and exp->exp2 into Qh.
#define QSCALE_ 0.18033688011112042f

typedef _Float16 v4h __attribute__((ext_vector_type(4)));
typedef _Float16 v8h __attribute__((ext_vector_type(8)));
typedef float    v4f __attribute__((ext_vector_type(4)));

// ---------------------------------------------------------------------------
// W[k][n] fp32 -> Wt[n][k] f16 (n-major so MFMA B-frags read contiguous k).
// ---------------------------------------------------------------------------
__global__ __launch_bounds__(256) void wtrans_kernel(const float* __restrict__ Wq,
                                                     const float* __restrict__ Wo,
                                                     _Float16* __restrict__ Wt) {
    __shared__ float Ts[64][65];
    const float* W = blockIdx.z ? Wo : Wq;
    _Float16* dst = Wt + (size_t)blockIdx.z * WSZ_;
    const int t = threadIdx.x;
    const int k0 = blockIdx.y * 64, n0 = blockIdx.x * 64;
#pragma unroll
    for (int i = 0; i < 4; i++) {
        int c = t + i * 256;
        int kk = c >> 4, nc = (c & 15) * 4;
        float4 w = *(const float4*)&W[(size_t)(k0 + kk) * 512 + n0 + nc];
        Ts[nc + 0][kk] = w.x;
        Ts[nc + 1][kk] = w.y;
        Ts[nc + 2][kk] = w.z;
        Ts[nc + 3][kk] = w.w;
    }
    __syncthreads();
#pragma unroll
    for (int i = 0; i < 2; i++) {
        int c = t + i * 256;
        int n = c >> 3, kc = (c & 7) * 8;
        v8h p;
#pragma unroll
        for (int j = 0; j < 8; j++) p[j] = (_Float16)Ts[n][kc + j];
        *(v8h*)&dst[(size_t)(n0 + n) * 512 + k0 + kc] = p;
    }
}

// ---------------------------------------------------------------------------
// Projection with fused fp32->f16 cast, VGPR-prefetch pipelined staging
// (the R8 flash pattern: next tile's global loads issue right after the
// staging barrier and overlap the current tile's MFMAs; no global_load_lds
// -> no vmcnt(0) drain; LDS padded to 40 halves -> conflict-free frag reads).
// 128x128 tile, BK=32, 4 waves (2x2), wave = 64x64.
// z in {0,1,2} -> Qh (pre-scaled) / Kh / VT [B,H,HD,S(permuted)].
// ---------------------------------------------------------------------------
__global__ __launch_bounds__(256) void proj_mfma(const float* __restrict__ q,
                                                 const float* __restrict__ k,
                                                 const float* __restrict__ v,
                                                 const _Float16* __restrict__ Wt,
                                                 const float* __restrict__ bq,
                                                 _Float16* __restrict__ Qh,
                                                 _Float16* __restrict__ Kh,
                                                 _Float16* __restrict__ VT) {
    __shared__ _Float16 As[128 * 40];
    __shared__ _Float16 Bs[128 * 40];
    const int z  = blockIdx.z;
    const float* X = (z == 0) ? q : ((z == 1) ? k : v);
    const int n0 = blockIdx.x * 128, m0 = blockIdx.y * 128;
    const int t    = threadIdx.x;
    const int lane = t & 63;
    const int w    = t >> 6;
    const int wm   = w >> 1, wn = w & 1;
    const int quad = lane >> 4, l16 = lane & 15;

    v4f acc[4][4];
#pragma unroll
    for (int mi = 0; mi < 4; mi++)
#pragma unroll
        for (int ni = 0; ni < 4; ni++) acc[mi][ni] = (v4f)0.f;

    const int s0 = t, s1 = t + 256;
    const int r0 = s0 >> 2, c0 = (s0 & 3) * 8;
    const int r1 = s1 >> 2, c1 = (s1 & 3) * 8;
    const float* A0 = X + (size_t)(m0 + r0) * 512 + c0;
    const float* A1 = X + (size_t)(m0 + r1) * 512 + c1;
    const _Float16* B0 = Wt + (size_t)(n0 + r0) * 512 + c0;
    const _Float16* B1 = Wt + (size_t)(n0 + r1) * 512 + c1;

    // Prologue: tile 0 into VGPRs
    v4f a00 = *(const v4f*)(A0 + 0), a01 = *(const v4f*)(A0 + 4);
    v4f a10 = *(const v4f*)(A1 + 0), a11 = *(const v4f*)(A1 + 4);
    v8h b0 = *(const v8h*)(B0 + 0), b1 = *(const v8h*)(B1 + 0);

    for (int k0 = 0; k0 < 512; k0 += 32) {
        v8h af0 = __builtin_shufflevector(__builtin_convertvector(a00, v4h),
                                          __builtin_convertvector(a01, v4h),
                                          0, 1, 2, 3, 4, 5, 6, 7);
        v8h af1 = __builtin_shufflevector(__builtin_convertvector(a10, v4h),
                                          __builtin_convertvector(a11, v4h),
                                          0, 1, 2, 3, 4, 5, 6, 7);
        __syncthreads();   // previous iteration's frag reads complete
        *(v8h*)&As[r0 * 40 + c0] = af0;
        *(v8h*)&As[r1 * 40 + c1] = af1;
        *(v8h*)&Bs[r0 * 40 + c0] = b0;
        *(v8h*)&Bs[r1 * 40 + c1] = b1;
        __syncthreads();   // staging visible

        if (k0 + 32 < 512) {   // prefetch next tile; latency overlaps MFMAs
            a00 = *(const v4f*)(A0 + k0 + 32); a01 = *(const v4f*)(A0 + k0 + 36);
            a10 = *(const v4f*)(A1 + k0 + 32); a11 = *(const v4f*)(A1 + k0 + 36);
            b0 = *(const v8h*)(B0 + k0 + 32);  b1 = *(const v8h*)(B1 + k0 + 32);
        }

        v8h af[4], bf[4];
#pragma unroll
        for (int mi = 0; mi < 4; mi++)
            af[mi] = *(const v8h*)&As[(wm * 64 + mi * 16 + l16) * 40 + quad * 8];
#pragma unroll
        for (int ni = 0; ni < 4; ni++)
            bf[ni] = *(const v8h*)&Bs[(wn * 64 + ni * 16 + l16) * 40 + quad * 8];
#pragma unroll
        for (int mi = 0; mi < 4; mi++)
#pragma unroll
            for (int ni = 0; ni < 4; ni++)
                acc[mi][ni] = __builtin_amdgcn_mfma_f32_16x16x32_f16(af[mi], bf[ni], acc[mi][ni], 0, 0, 0);
    }

    if (z < 2) {
        _Float16* Y = z ? Kh : Qh;
        const float sc = z ? 1.f : QSCALE_;
#pragma unroll
        for (int mi = 0; mi < 4; mi++) {
            int mb = m0 + wm * 64 + mi * 16 + quad * 4;
#pragma unroll
            for (int ni = 0; ni < 4; ni++) {
                int n = n0 + wn * 64 + ni * 16 + l16;
                float bj = bq[n];
#pragma unroll
                for (int r = 0; r < 4; r++)
                    Y[(size_t)(mb + r) * 512 + n] = (_Float16)((acc[mi][ni][r] + bj) * sc);
            }
        }
    } else {
#pragma unroll
        for (int mi = 0; mi < 4; mi++) {
            int tile0 = (m0 & 2047) + wm * 64;
            int pos = tile0 + (mi >> 1) * 32 + quad * 8 + (mi & 1) * 4;
            int b = m0 >> 11;
#pragma unroll
            for (int ni = 0; ni < 4; ni++) {
                int n = n0 + wn * 64 + ni * 16 + l16;
                int h = n >> 6, d = n & 63;
                float bj = bq[n];
                v4h pk;
#pragma unroll
                for (int r = 0; r < 4; r++) pk[r] = (_Float16)(acc[mi][ni][r] + bj);
                *(v4h*)&VT[(((size_t)b * H_ + h) * HD_ + d) * S_ + pos] = pk;
            }
        }
    }
}

// ---------------------------------------------------------------------------
// Output projection with fused split-K combine, same prefetch-pipelined
// staging. A[m,k] = (O1+O2)[m,k] * linv computed during staging.
// ---------------------------------------------------------------------------
__global__ __launch_bounds__(256) void outproj_mfma(const float* __restrict__ Op,
                                                    const float* __restrict__ lp,
                                                    const _Float16* __restrict__ Wt,
                                                    const float* __restrict__ bo,
                                                    float* __restrict__ out) {
    __shared__ _Float16 As[128 * 40];
    __shared__ _Float16 Bs[128 * 40];
    const int n0 = blockIdx.x * 128, m0 = blockIdx.y * 128;
    const int t    = threadIdx.x;
    const int lane = t & 63;
    const int w    = t >> 6;
    const int wm   = w >> 1, wn = w & 1;
    const int quad = lane >> 4, l16 = lane & 15;

    v4f acc[4][4];
#pragma unroll
    for (int mi = 0; mi < 4; mi++)
#pragma unroll
        for (int ni = 0; ni < 4; ni++) acc[mi][ni] = (v4f)0.f;

    const int s0 = t, s1 = t + 256;
    const int r0 = s0 >> 2, c0 = (s0 & 3) * 8;
    const int r1 = s1 >> 2, c1 = (s1 & 3) * 8;
    const float* O10 = Op + (size_t)(m0 + r0) * 512 + c0;
    const float* O11 = Op + (size_t)(m0 + r1) * 512 + c1;
    const float* O20 = O10 + SZ_;
    const float* O21 = O11 + SZ_;
    const float* lp0 = lp + (size_t)(m0 + r0) * H_;
    const float* lp1 = lp + (size_t)(m0 + r1) * H_;
    const _Float16* B0 = Wt + (size_t)WSZ_ + (size_t)(n0 + r0) * 512 + c0;
    const _Float16* B1 = Wt + (size_t)WSZ_ + (size_t)(n0 + r1) * 512 + c1;

    // Prologue: tile 0
    v4f a00 = *(const v4f*)(O10 + 0), a01 = *(const v4f*)(O10 + 4);
    v4f a10 = *(const v4f*)(O11 + 0), a11 = *(const v4f*)(O11 + 4);
    v4f c00 = *(const v4f*)(O20 + 0), c01 = *(const v4f*)(O20 + 4);
    v4f c10 = *(const v4f*)(O21 + 0), c11 = *(const v4f*)(O21 + 4);
    float lv0 = lp0[0] + lp0[BSH_], lv1 = lp1[0] + lp1[BSH_];
    v8h b0 = *(const v8h*)(B0 + 0), b1 = *(const v8h*)(B1 + 0);

    for (int k0 = 0; k0 < 512; k0 += 32) {
        float linv0 = __builtin_amdgcn_rcpf(lv0);
        float linv1 = __builtin_amdgcn_rcpf(lv1);
        v4f s0a = (a00 + c00) * linv0, s0b = (a01 + c01) * linv0;
        v4f s1a = (a10 + c10) * linv1, s1b = (a11 + c11) * linv1;
        v8h af0 = __builtin_shufflevector(__builtin_convertvector(s0a, v4h),
                                          __builtin_convertvector(s0b, v4h),
                                          0, 1, 2, 3, 4, 5, 6, 7);
        v8h af1 = __builtin_shufflevector(__builtin_convertvector(s1a, v4h),
                                          __builtin_convertvector(s1b, v4h),
                                          0, 1, 2, 3, 4, 5, 6, 7);
        __syncthreads();
        *(v8h*)&As[r0 * 40 + c0] = af0;
        *(v8h*)&As[r1 * 40 + c1] = af1;
        *(v8h*)&Bs[r0 * 40 + c0] = b0;
        *(v8h*)&Bs[r1 * 40 + c1] = b1;
        __syncthreads();

        if (k0 + 32 < 512) {
            int kn = k0 + 32;
            int hh = kn >> 6;   // head index uniform per iter: c<32, (kn&32)+c<64
            a00 = *(const v4f*)(O10 + kn); a01 = *(const v4f*)(O10 + kn + 4);
            a10 = *(const v4f*)(O11 + kn); a11 = *(const v4f*)(O11 + kn + 4);
            c00 = *(const v4f*)(O20 + kn); c01 = *(const v4f*)(O20 + kn + 4);
            c10 = *(const v4f*)(O21 + kn); c11 = *(const v4f*)(O21 + kn + 4);
            lv0 = lp0[hh] + lp0[BSH_ + hh];
            lv1 = lp1[hh] + lp1[BSH_ + hh];
            b0 = *(const v8h*)(B0 + kn);
            b1 = *(const v8h*)(B1 + kn);
        }

        v8h af[4], bf[4];
#pragma unroll
        for (int mi = 0; mi < 4; mi++)
            af[mi] = *(const v8h*)&As[(wm * 64 + mi * 16 + l16) * 40 + quad * 8];
#pragma unroll
        for (int ni = 0; ni < 4; ni++)
            bf[ni] = *(const v8h*)&Bs[(wn * 64 + ni * 16 + l16) * 40 + quad * 8];
#pragma unroll
        for (int mi = 0; mi < 4; mi++)
#pragma unroll
            for (int ni = 0; ni < 4; ni++)
                acc[mi][ni] = __builtin_amdgcn_mfma_f32_16x16x32_f16(af[mi], bf[ni], acc[mi][ni], 0, 0, 0);
    }

#pragma unroll
    for (int mi = 0; mi < 4; mi++) {
        int mb = m0 + wm * 64 + mi * 16 + quad * 4;
#pragma unroll
        for (int ni = 0; ni < 4; ni++) {
            int n = n0 + wn * 64 + ni * 16 + l16;
            float bj = bo[n];
#pragma unroll
            for (int r = 0; r < 4; r++)
                out[(size_t)(mb + r) * 512 + n] = acc[mi][ni][r] + bj;
        }
    }
}

// ---------------------------------------------------------------------------
// Split-K MFMA f16 flash attention (unchanged from R8: 57.9 µs, verified).
// ---------------------------------------------------------------------------
__global__ __launch_bounds__(256) void flash_attn_f16(const _Float16* __restrict__ Qh,
                                                      const _Float16* __restrict__ Kh,
                                                      const _Float16* __restrict__ VT,
                                                      float* __restrict__ Op,
                                                      float* __restrict__ lp) {
    __shared__ _Float16 Ks[128 * 72];    // [key][d], pad 72
    __shared__ _Float16 Vs[64 * 136];    // [d][pos], pad 136

    const int t     = threadIdx.x;
    const int lane  = t & 63;
    const int w     = t >> 6;
    const int quad  = lane >> 4;
    const int l16   = lane & 15;
    const int q0    = blockIdx.x * 128;
    const int h     = blockIdx.y;
    const int b     = blockIdx.z >> 1;
    const int split = blockIdx.z & 1;

    const size_t base  = (size_t)b * S_ * D_ + (size_t)h * HD_;
    const size_t vbase = ((size_t)b * H_ + h) * HD_ * (size_t)S_;

    v8h qf[2][2];
#pragma unroll
    for (int nb = 0; nb < 2; nb++) {
        const _Float16* qrow = Qh + base + (size_t)(q0 + w * 32 + nb * 16 + l16) * D_;
        qf[nb][0] = *(const v8h*)(qrow + quad * 8);
        qf[nb][1] = *(const v8h*)(qrow + 32 + quad * 8);
    }

    v4f o[2][4];
#pragma unroll
    for (int nb = 0; nb < 2; nb++)
#pragma unroll
        for (int i = 0; i < 4; i++) o[nb][i] = (v4f)0.f;
    float l_lane[2] = {0.f, 0.f};

    const int kbeg = split * (S_ / 2);
    const int kend = kbeg + S_ / 2;

    v8h kv[4], vv[4];
#define LOADKV(kk)                                                             \
    do {                                                                       \
        _Pragma("unroll") for (int i = 0; i < 4; i++) {                        \
            int c = t + i * 256;                                               \
            kv[i] = *(const v8h*)(Kh + base + (size_t)((kk) + (c >> 3)) * D_ + (c & 7) * 8); \
            vv[i] = *(const v8h*)(VT + vbase + (size_t)(c >> 4) * S_ + (kk) + (c & 15) * 8); \
        }                                                                      \
    } while (0)

    LOADKV(kbeg);

    for (int kk0 = kbeg; kk0 < kend; kk0 += 128) {
        __syncthreads();
#pragma unroll
        for (int i = 0; i < 4; i++) {
            int c = t + i * 256;
            *(v8h*)&Ks[(c >> 3) * 72 + (c & 7) * 8] = kv[i];
            *(v8h*)&Vs[(c >> 4) * 136 + (c & 15) * 8] = vv[i];
        }
        __syncthreads();

        if (kk0 + 128 < kend) LOADKV(kk0 + 128);

#pragma unroll
        for (int hh = 0; hh < 2; hh++) {
            v4f sc[4][2];
#pragma unroll
            for (int mb = 0; mb < 4; mb++)
#pragma unroll
                for (int nb = 0; nb < 2; nb++) sc[mb][nb] = (v4f)0.f;
#pragma unroll
            for (int ks = 0; ks < 2; ks++) {
#pragma unroll
                for (int mb = 0; mb < 4; mb++) {
                    v8h ak = *(const v8h*)&Ks[(hh * 64 + mb * 16 + l16) * 72 + ks * 32 + quad * 8];
#pragma unroll
                    for (int nb = 0; nb < 2; nb++)
                        sc[mb][nb] = __builtin_amdgcn_mfma_f32_16x16x32_f16(ak, qf[nb][ks], sc[mb][nb], 0, 0, 0);
                }
            }

            v4h pf[4][2];
#pragma unroll
            for (int nb = 0; nb < 2; nb++) {
#pragma unroll
                for (int mb = 0; mb < 4; mb++) {
                    v4f pv;
#pragma unroll
                    for (int r = 0; r < 4; r++) pv[r] = __builtin_amdgcn_exp2f(sc[mb][nb][r]);
                    pf[mb][nb] = __builtin_convertvector(pv, v4h);
                    l_lane[nb] += (pv[0] + pv[1]) + (pv[2] + pv[3]);
                }
            }

#pragma unroll
            for (int p = 0; p < 2; p++) {
#pragma unroll
                for (int dblk = 0; dblk < 4; dblk++) {
                    v8h vf2 = *(const v8h*)&Vs[(dblk * 16 + l16) * 136 + hh * 64 + p * 32 + quad * 8];
                    v4h vlo = __builtin_shufflevector(vf2, vf2, 0, 1, 2, 3);
                    v4h vhi = __builtin_shufflevector(vf2, vf2, 4, 5, 6, 7);
#pragma unroll
                    for (int nb = 0; nb < 2; nb++) {
                        o[nb][dblk] = __builtin_amdgcn_mfma_f32_16x16x16f16(vlo, pf[2 * p][nb], o[nb][dblk], 0, 0, 0);
                        o[nb][dblk] = __builtin_amdgcn_mfma_f32_16x16x16f16(vhi, pf[2 * p + 1][nb], o[nb][dblk], 0, 0, 0);
                    }
                }
            }
        }
    }
#undef LOADKV

    float* Ops = Op + (size_t)split * SZ_;
#pragma unroll
    for (int nb = 0; nb < 2; nb++) {
        float rs = l_lane[nb];
        rs += __shfl_xor(rs, 16);
        rs += __shfl_xor(rs, 32);
        int qrow = q0 + w * 32 + nb * 16 + l16;
        if (quad == 0)
            lp[(size_t)split * BSH_ + ((size_t)b * S_ + qrow) * H_ + h] = rs;
        const size_t rbase = base + (size_t)qrow * D_;
#pragma unroll
        for (int dblk = 0; dblk < 4; dblk++)
            *(v4f*)&Ops[rbase + dblk * 16 + quad * 4] = o[nb][dblk];
    }
}

extern "C" void kernel_launch(void* const* d_in, const int* in_sizes, int n_in,
                              void* d_out, int out_size, void* d_ws, size_t ws_size,
                              hipStream_t stream) {
    const float* query = (const float*)d_in[0];
    const float* key   = (const float*)d_in[1];
    const float* value = (const float*)d_in[2];
    const float* Wq    = (const float*)d_in[3];
    const float* bq    = (const float*)d_in[4];
    const float* Wo    = (const float*)d_in[5];
    const float* bo    = (const float*)d_in[6];
    float* out = (float*)d_out;

    _Float16* ws = (_Float16*)d_ws;
    _Float16* Qh = ws;                                   // [B,S,D] f16
    _Float16* Kh = ws + (size_t)SZ_;                     // [B,S,D] f16
    _Float16* VT = ws + 2 * (size_t)SZ_;                 // [B,H,HD,S] f16 (permuted)
    _Float16* Wt = ws + 3 * (size_t)SZ_;                 // 2x[N,K] f16
    float*    Op = (float*)(ws + 3 * (size_t)SZ_ + 2 * (size_t)WSZ_);  // 2x[B,S,D] f32
    float*    lp = Op + 2 * (size_t)SZ_;                 // 2x[B,S,H] f32

    wtrans_kernel<<<dim3(8, 8, 2), 256, 0, stream>>>(Wq, Wo, Wt);
    proj_mfma<<<dim3(4, 64, 3), 256, 0, stream>>>(query, key, value, Wt, bq, Qh, Kh, VT);
    flash_attn_f16<<<dim3(S_ / 128, H_, B_ * 2), 256, 0, stream>>>(Qh, Kh, VT, Op, lp);
    outproj_mfma<<<dim3(4, 64, 1), 256, 0, stream>>>(Op, lp, Wt, bo, out);
}

// Round 10
// 205.057 us; speedup vs baseline: 1.0541x; 1.0323x over previous
//
#include <hip/hip_runtime.h>
#include <math.h>

#define B_ 4
#define S_ 2048
#define D_ 512
#define H_ 8
#define HD_ 64
#define SZ_ (B_ * S_ * D_)
#define WSZ_ (D_ * D_)   // 262144
#define BSH_ (B_ * S_ * H_)

// 0.125 * log2(e): folds the 1/sqrt(64) score scale and exp->exp2 into Qh.
#define QSCALE_ 0.18033688011112042f

typedef _Float16 v4h __attribute__((ext_vector_type(4)));
typedef _Float16 v8h __attribute__((ext_vector_type(8)));
typedef float    v4f __attribute__((ext_vector_type(4)));

// ---------------------------------------------------------------------------
// W[k][n] fp32 -> Wt[n][k] f16 (n-major so MFMA B-frags read contiguous k).
// ---------------------------------------------------------------------------
__global__ __launch_bounds__(256) void wtrans_kernel(const float* __restrict__ Wq,
                                                     const float* __restrict__ Wo,
                                                     _Float16* __restrict__ Wt) {
    __shared__ float Ts[64][65];
    const float* W = blockIdx.z ? Wo : Wq;
    _Float16* dst = Wt + (size_t)blockIdx.z * WSZ_;
    const int t = threadIdx.x;
    const int k0 = blockIdx.y * 64, n0 = blockIdx.x * 64;
#pragma unroll
    for (int i = 0; i < 4; i++) {
        int c = t + i * 256;
        int kk = c >> 4, nc = (c & 15) * 4;
        float4 w = *(const float4*)&W[(size_t)(k0 + kk) * 512 + n0 + nc];
        Ts[nc + 0][kk] = w.x;
        Ts[nc + 1][kk] = w.y;
        Ts[nc + 2][kk] = w.z;
        Ts[nc + 3][kk] = w.w;
    }
    __syncthreads();
#pragma unroll
    for (int i = 0; i < 2; i++) {
        int c = t + i * 256;
        int n = c >> 3, kc = (c & 7) * 8;
        v8h p;
#pragma unroll
        for (int j = 0; j < 8; j++) p[j] = (_Float16)Ts[n][kc + j];
        *(v8h*)&dst[(size_t)(n0 + n) * 512 + k0 + kc] = p;
    }
}

// ---------------------------------------------------------------------------
// Projection with fused fp32->f16 cast. R10: BK=64 — 8 K-iterations, 32 MFMAs
// per wave per barrier-pair (halves the barrier drains vs BK=32; the short
// 16-iter loop with only 16 MFMAs/drain was the amortization gap vs m97).
// 128x128 tile, 4 waves (2x2), wave = 64x64. 1-deep VGPR prefetch kept.
// z in {0,1,2} -> Qh (pre-scaled) / Kh / VT [B,H,HD,S(permuted)].
// ---------------------------------------------------------------------------
__global__ __launch_bounds__(256) void proj_mfma(const float* __restrict__ q,
                                                 const float* __restrict__ k,
                                                 const float* __restrict__ v,
                                                 const _Float16* __restrict__ Wt,
                                                 const float* __restrict__ bq,
                                                 _Float16* __restrict__ Qh,
                                                 _Float16* __restrict__ Kh,
                                                 _Float16* __restrict__ VT) {
    __shared__ _Float16 As[128 * 72];
    __shared__ _Float16 Bs[128 * 72];
    const int z  = blockIdx.z;
    const float* X = (z == 0) ? q : ((z == 1) ? k : v);
    const int n0 = blockIdx.x * 128, m0 = blockIdx.y * 128;
    const int t    = threadIdx.x;
    const int lane = t & 63;
    const int w    = t >> 6;
    const int wm   = w >> 1, wn = w & 1;
    const int quad = lane >> 4, l16 = lane & 15;

    v4f acc[4][4];
#pragma unroll
    for (int mi = 0; mi < 4; mi++)
#pragma unroll
        for (int ni = 0; ni < 4; ni++) acc[mi][ni] = (v4f)0.f;

    // 4 slots/thread: slot s = t + i*256, row = s>>3, half-chunk = (s&7)*8
    int rr[4], cc[4];
    const float*    Ap[4];
    const _Float16* Bp[4];
#pragma unroll
    for (int i = 0; i < 4; i++) {
        int s = t + i * 256;
        rr[i] = s >> 3;
        cc[i] = (s & 7) * 8;
        Ap[i] = X + (size_t)(m0 + rr[i]) * 512 + cc[i];
        Bp[i] = Wt + (size_t)(n0 + rr[i]) * 512 + cc[i];
    }

    // Prologue: tile 0 into VGPRs
    v4f pa[4][2];
    v8h pb[4];
#pragma unroll
    for (int i = 0; i < 4; i++) {
        pa[i][0] = *(const v4f*)(Ap[i] + 0);
        pa[i][1] = *(const v4f*)(Ap[i] + 4);
        pb[i]    = *(const v8h*)(Bp[i] + 0);
    }

    for (int k0 = 0; k0 < 512; k0 += 64) {
        v8h af4[4];
#pragma unroll
        for (int i = 0; i < 4; i++)
            af4[i] = __builtin_shufflevector(__builtin_convertvector(pa[i][0], v4h),
                                             __builtin_convertvector(pa[i][1], v4h),
                                             0, 1, 2, 3, 4, 5, 6, 7);
        __syncthreads();   // previous iteration's frag reads complete
#pragma unroll
        for (int i = 0; i < 4; i++) {
            *(v8h*)&As[rr[i] * 72 + cc[i]] = af4[i];
            *(v8h*)&Bs[rr[i] * 72 + cc[i]] = pb[i];
        }
        __syncthreads();   // staging visible

        if (k0 + 64 < 512) {   // prefetch next tile; overlaps 32 MFMAs below
#pragma unroll
            for (int i = 0; i < 4; i++) {
                pa[i][0] = *(const v4f*)(Ap[i] + k0 + 64);
                pa[i][1] = *(const v4f*)(Ap[i] + k0 + 68);
                pb[i]    = *(const v8h*)(Bp[i] + k0 + 64);
            }
        }

#pragma unroll
        for (int ks = 0; ks < 2; ks++) {
            v8h af[4], bf[4];
#pragma unroll
            for (int mi = 0; mi < 4; mi++)
                af[mi] = *(const v8h*)&As[(wm * 64 + mi * 16 + l16) * 72 + ks * 32 + quad * 8];
#pragma unroll
            for (int ni = 0; ni < 4; ni++)
                bf[ni] = *(const v8h*)&Bs[(wn * 64 + ni * 16 + l16) * 72 + ks * 32 + quad * 8];
#pragma unroll
            for (int mi = 0; mi < 4; mi++)
#pragma unroll
                for (int ni = 0; ni < 4; ni++)
                    acc[mi][ni] = __builtin_amdgcn_mfma_f32_16x16x32_f16(af[mi], bf[ni], acc[mi][ni], 0, 0, 0);
        }
    }

    if (z < 2) {
        _Float16* Y = z ? Kh : Qh;
        const float sc = z ? 1.f : QSCALE_;
#pragma unroll
        for (int mi = 0; mi < 4; mi++) {
            int mb = m0 + wm * 64 + mi * 16 + quad * 4;
#pragma unroll
            for (int ni = 0; ni < 4; ni++) {
                int n = n0 + wn * 64 + ni * 16 + l16;
                float bj = bq[n];
#pragma unroll
                for (int r = 0; r < 4; r++)
                    Y[(size_t)(mb + r) * 512 + n] = (_Float16)((acc[mi][ni][r] + bj) * sc);
            }
        }
    } else {
#pragma unroll
        for (int mi = 0; mi < 4; mi++) {
            int tile0 = (m0 & 2047) + wm * 64;
            int pos = tile0 + (mi >> 1) * 32 + quad * 8 + (mi & 1) * 4;
            int b = m0 >> 11;
#pragma unroll
            for (int ni = 0; ni < 4; ni++) {
                int n = n0 + wn * 64 + ni * 16 + l16;
                int h = n >> 6, d = n & 63;
                float bj = bq[n];
                v4h pk;
#pragma unroll
                for (int r = 0; r < 4; r++) pk[r] = (_Float16)(acc[mi][ni][r] + bj);
                *(v4h*)&VT[(((size_t)b * H_ + h) * HD_ + d) * S_ + pos] = pk;
            }
        }
    }
}

// ---------------------------------------------------------------------------
// Output projection with fused split-K combine. R10: 64x128 tile, grid 512
// (2 blocks/CU — the old 256-block grid was 1 block/CU = 4 waves/CU, an
// occupancy floor with nothing to hide the barrier drains).
// Waves 2x2: wave = 32m x 64n, acc[2][4]. BK=32, 1-deep prefetch.
// ---------------------------------------------------------------------------
__global__ __launch_bounds__(256) void outproj_mfma(const float* __restrict__ Op,
                                                    const float* __restrict__ lp,
                                                    const _Float16* __restrict__ Wt,
                                                    const float* __restrict__ bo,
                                                    float* __restrict__ out) {
    __shared__ _Float16 As[64 * 40];
    __shared__ _Float16 Bs[128 * 40];
    const int n0 = blockIdx.x * 128, m0 = blockIdx.y * 64;
    const int t    = threadIdx.x;
    const int lane = t & 63;
    const int w    = t >> 6;
    const int wm   = w >> 1, wn = w & 1;
    const int quad = lane >> 4, l16 = lane & 15;

    v4f acc[2][4];
#pragma unroll
    for (int mi = 0; mi < 2; mi++)
#pragma unroll
        for (int ni = 0; ni < 4; ni++) acc[mi][ni] = (v4f)0.f;

    // A: 64 rows x 4 chunks = 256 slots (1/thread); B: 128 x 4 = 512 (2/thread)
    const int ra = t >> 2,  ca = (t & 3) * 8;
    const int rb0 = t >> 2, cb0 = (t & 3) * 8;
    const int rb1 = (t + 256) >> 2, cb1 = (t & 3) * 8;
    const float* O1p = Op + (size_t)(m0 + ra) * 512 + ca;
    const float* O2p = O1p + SZ_;
    const float* lpp = lp + (size_t)(m0 + ra) * H_;
    const _Float16* B0 = Wt + (size_t)WSZ_ + (size_t)(n0 + rb0) * 512 + cb0;
    const _Float16* B1 = Wt + (size_t)WSZ_ + (size_t)(n0 + rb1) * 512 + cb1;

    // Prologue: tile 0
    v4f a0 = *(const v4f*)(O1p + 0), a1 = *(const v4f*)(O1p + 4);
    v4f c0 = *(const v4f*)(O2p + 0), c1 = *(const v4f*)(O2p + 4);
    float lv = lpp[0] + lpp[BSH_];
    v8h b0 = *(const v8h*)(B0 + 0), b1 = *(const v8h*)(B1 + 0);

    for (int k0 = 0; k0 < 512; k0 += 32) {
        float linv = __builtin_amdgcn_rcpf(lv);
        v4f sa = (a0 + c0) * linv, sb = (a1 + c1) * linv;
        v8h af0 = __builtin_shufflevector(__builtin_convertvector(sa, v4h),
                                          __builtin_convertvector(sb, v4h),
                                          0, 1, 2, 3, 4, 5, 6, 7);
        __syncthreads();
        *(v8h*)&As[ra * 40 + ca] = af0;
        *(v8h*)&Bs[rb0 * 40 + cb0] = b0;
        *(v8h*)&Bs[rb1 * 40 + cb1] = b1;
        __syncthreads();

        if (k0 + 32 < 512) {
            int kn = k0 + 32;
            int hh = (kn + ca) >> 6;   // ca<32, kn%32==0 -> uniform head per load
            a0 = *(const v4f*)(O1p + kn); a1 = *(const v4f*)(O1p + kn + 4);
            c0 = *(const v4f*)(O2p + kn); c1 = *(const v4f*)(O2p + kn + 4);
            lv = lpp[hh] + lpp[BSH_ + hh];
            b0 = *(const v8h*)(B0 + kn);
            b1 = *(const v8h*)(B1 + kn);
        }

        v8h af[2], bf[4];
#pragma unroll
        for (int mi = 0; mi < 2; mi++)
            af[mi] = *(const v8h*)&As[(wm * 32 + mi * 16 + l16) * 40 + quad * 8];
#pragma unroll
        for (int ni = 0; ni < 4; ni++)
            bf[ni] = *(const v8h*)&Bs[(wn * 64 + ni * 16 + l16) * 40 + quad * 8];
#pragma unroll
        for (int mi = 0; mi < 2; mi++)
#pragma unroll
            for (int ni = 0; ni < 4; ni++)
                acc[mi][ni] = __builtin_amdgcn_mfma_f32_16x16x32_f16(af[mi], bf[ni], acc[mi][ni], 0, 0, 0);
    }

#pragma unroll
    for (int mi = 0; mi < 2; mi++) {
        int mb = m0 + wm * 32 + mi * 16 + quad * 4;
#pragma unroll
        for (int ni = 0; ni < 4; ni++) {
            int n = n0 + wn * 64 + ni * 16 + l16;
            float bj = bo[n];
#pragma unroll
            for (int r = 0; r < 4; r++)
                out[(size_t)(mb + r) * 512 + n] = acc[mi][ni][r] + bj;
        }
    }
}

// ---------------------------------------------------------------------------
// Split-K MFMA f16 flash attention (FROZEN from R8: 57.9 µs verified).
// ---------------------------------------------------------------------------
__global__ __launch_bounds__(256) void flash_attn_f16(const _Float16* __restrict__ Qh,
                                                      const _Float16* __restrict__ Kh,
                                                      const _Float16* __restrict__ VT,
                                                      float* __restrict__ Op,
                                                      float* __restrict__ lp) {
    __shared__ _Float16 Ks[128 * 72];    // [key][d], pad 72
    __shared__ _Float16 Vs[64 * 136];    // [d][pos], pad 136

    const int t     = threadIdx.x;
    const int lane  = t & 63;
    const int w     = t >> 6;
    const int quad  = lane >> 4;
    const int l16   = lane & 15;
    const int q0    = blockIdx.x * 128;
    const int h     = blockIdx.y;
    const int b     = blockIdx.z >> 1;
    const int split = blockIdx.z & 1;

    const size_t base  = (size_t)b * S_ * D_ + (size_t)h * HD_;
    const size_t vbase = ((size_t)b * H_ + h) * HD_ * (size_t)S_;

    v8h qf[2][2];
#pragma unroll
    for (int nb = 0; nb < 2; nb++) {
        const _Float16* qrow = Qh + base + (size_t)(q0 + w * 32 + nb * 16 + l16) * D_;
        qf[nb][0] = *(const v8h*)(qrow + quad * 8);
        qf[nb][1] = *(const v8h*)(qrow + 32 + quad * 8);
    }

    v4f o[2][4];
#pragma unroll
    for (int nb = 0; nb < 2; nb++)
#pragma unroll
        for (int i = 0; i < 4; i++) o[nb][i] = (v4f)0.f;
    float l_lane[2] = {0.f, 0.f};

    const int kbeg = split * (S_ / 2);
    const int kend = kbeg + S_ / 2;

    v8h kv[4], vv[4];
#define LOADKV(kk)                                                             \
    do {                                                                       \
        _Pragma("unroll") for (int i = 0; i < 4; i++) {                        \
            int c = t + i * 256;                                               \
            kv[i] = *(const v8h*)(Kh + base + (size_t)((kk) + (c >> 3)) * D_ + (c & 7) * 8); \
            vv[i] = *(const v8h*)(VT + vbase + (size_t)(c >> 4) * S_ + (kk) + (c & 15) * 8); \
        }                                                                      \
    } while (0)

    LOADKV(kbeg);

    for (int kk0 = kbeg; kk0 < kend; kk0 += 128) {
        __syncthreads();
#pragma unroll
        for (int i = 0; i < 4; i++) {
            int c = t + i * 256;
            *(v8h*)&Ks[(c >> 3) * 72 + (c & 7) * 8] = kv[i];
            *(v8h*)&Vs[(c >> 4) * 136 + (c & 15) * 8] = vv[i];
        }
        __syncthreads();

        if (kk0 + 128 < kend) LOADKV(kk0 + 128);

#pragma unroll
        for (int hh = 0; hh < 2; hh++) {
            v4f sc[4][2];
#pragma unroll
            for (int mb = 0; mb < 4; mb++)
#pragma unroll
                for (int nb = 0; nb < 2; nb++) sc[mb][nb] = (v4f)0.f;
#pragma unroll
            for (int ks = 0; ks < 2; ks++) {
#pragma unroll
                for (int mb = 0; mb < 4; mb++) {
                    v8h ak = *(const v8h*)&Ks[(hh * 64 + mb * 16 + l16) * 72 + ks * 32 + quad * 8];
#pragma unroll
                    for (int nb = 0; nb < 2; nb++)
                        sc[mb][nb] = __builtin_amdgcn_mfma_f32_16x16x32_f16(ak, qf[nb][ks], sc[mb][nb], 0, 0, 0);
                }
            }

            v4h pf[4][2];
#pragma unroll
            for (int nb = 0; nb < 2; nb++) {
#pragma unroll
                for (int mb = 0; mb < 4; mb++) {
                    v4f pv;
#pragma unroll
                    for (int r = 0; r < 4; r++) pv[r] = __builtin_amdgcn_exp2f(sc[mb][nb][r]);
                    pf[mb][nb] = __builtin_convertvector(pv, v4h);
                    l_lane[nb] += (pv[0] + pv[1]) + (pv[2] + pv[3]);
                }
            }

#pragma unroll
            for (int p = 0; p < 2; p++) {
#pragma unroll
                for (int dblk = 0; dblk < 4; dblk++) {
                    v8h vf2 = *(const v8h*)&Vs[(dblk * 16 + l16) * 136 + hh * 64 + p * 32 + quad * 8];
                    v4h vlo = __builtin_shufflevector(vf2, vf2, 0, 1, 2, 3);
                    v4h vhi = __builtin_shufflevector(vf2, vf2, 4, 5, 6, 7);
#pragma unroll
                    for (int nb = 0; nb < 2; nb++) {
                        o[nb][dblk] = __builtin_amdgcn_mfma_f32_16x16x16f16(vlo, pf[2 * p][nb], o[nb][dblk], 0, 0, 0);
                        o[nb][dblk] = __builtin_amdgcn_mfma_f32_16x16x16f16(vhi, pf[2 * p + 1][nb], o[nb][dblk], 0, 0, 0);
                    }
                }
            }
        }
    }
#undef LOADKV

    float* Ops = Op + (size_t)split * SZ_;
#pragma unroll
    for (int nb = 0; nb < 2; nb++) {
        float rs = l_lane[nb];
        rs += __shfl_xor(rs, 16);
        rs += __shfl_xor(rs, 32);
        int qrow = q0 + w * 32 + nb * 16 + l16;
        if (quad == 0)
            lp[(size_t)split * BSH_ + ((size_t)b * S_ + qrow) * H_ + h] = rs;
        const size_t rbase = base + (size_t)qrow * D_;
#pragma unroll
        for (int dblk = 0; dblk < 4; dblk++)
            *(v4f*)&Ops[rbase + dblk * 16 + quad * 4] = o[nb][dblk];
    }
}

extern "C" void kernel_launch(void* const* d_in, const int* in_sizes, int n_in,
                              void* d_out, int out_size, void* d_ws, size_t ws_size,
                              hipStream_t stream) {
    const float* query = (const float*)d_in[0];
    const float* key   = (const float*)d_in[1];
    const float* value = (const float*)d_in[2];
    const float* Wq    = (const float*)d_in[3];
    const float* bq    = (const float*)d_in[4];
    const float* Wo    = (const float*)d_in[5];
    const float* bo    = (const float*)d_in[6];
    float* out = (float*)d_out;

    _Float16* ws = (_Float16*)d_ws;
    _Float16* Qh = ws;                                   // [B,S,D] f16
    _Float16* Kh = ws + (size_t)SZ_;                     // [B,S,D] f16
    _Float16* VT = ws + 2 * (size_t)SZ_;                 // [B,H,HD,S] f16 (permuted)
    _Float16* Wt = ws + 3 * (size_t)SZ_;                 // 2x[N,K] f16
    float*    Op = (float*)(ws + 3 * (size_t)SZ_ + 2 * (size_t)WSZ_);  // 2x[B,S,D] f32
    float*    lp = Op + 2 * (size_t)SZ_;                 // 2x[B,S,H] f32

    wtrans_kernel<<<dim3(8, 8, 2), 256, 0, stream>>>(Wq, Wo, Wt);
    proj_mfma<<<dim3(4, 64, 3), 256, 0, stream>>>(query, key, value, Wt, bq, Qh, Kh, VT);
    flash_attn_f16<<<dim3(S_ / 128, H_, B_ * 2), 256, 0, stream>>>(Qh, Kh, VT, Op, lp);
    outproj_mfma<<<dim3(4, 128, 1), 256, 0, stream>>>(Op, lp, Wt, bo, out);
}